// Round 1
// 333.062 us; speedup vs baseline: 1.0164x; 1.0164x over previous
//
#include <hip/hip_runtime.h>
#include <math.h>

// ---------------------------------------------------------------------------
// gram = x^T x (N=4M, D=10, fp64-accurate reduction) -> fp32 -> LAPACK-
// faithful fp32 ssyevd path (ssytd2 'L' + ssteqr, LAPACK>=3.10 slartg) -> MLP.
// Round 6 (gram): drop the LDS transpose stage entirely. Each thread loads
// its 2 rows (5 aligned float4, stride 80B) DIRECTLY from global, with an
// explicit register double-buffer (issue tile t+1's loads before computing
// tile t). This removes the two barriers + vmcnt(0) drain per 20KB tile that
// made the old kernel latency-bound (1.7 TB/s effective). Row->thread mapping
// and accumulation order are bitwise-identical to the passing round-5 kernel.
// ---------------------------------------------------------------------------

#define BLK2 256
#define GRID2 1024
#define TILE_F4 (BLK2 * 5)  // 1280 float4 = 5120 floats = 512 rows per tile

__global__ void zero_ws_kernel(double* __restrict__ g) {
  int t = threadIdx.x;
  if (t < 220) g[t] = 0.0;
}

__global__ __launch_bounds__(BLK2) void gram_kernel(const float4* __restrict__ x4,
                                                    double* __restrict__ g,
                                                    int nf4) {
  float acc[55];
#pragma unroll
  for (int k = 0; k < 55; k++) acc[k] = 0.0f;

  const int tid = threadIdx.x;
  const int ntiles = (nf4 + TILE_F4 - 1) / TILE_F4;
  const float4 zz = make_float4(0.f, 0.f, 0.f, 0.f);

  int t = (int)blockIdx.x;
  bool active = (t < ntiles);

  // prefetch current tile's 5 float4 (thread's 2 rows, 80B contiguous)
  float4 c0 = zz, c1 = zz, c2 = zz, c3 = zz, c4 = zz;
  if (active) {
    int b = t * TILE_F4 + tid * 5;
    c0 = (b + 0 < nf4) ? x4[b + 0] : zz;
    c1 = (b + 1 < nf4) ? x4[b + 1] : zz;
    c2 = (b + 2 < nf4) ? x4[b + 2] : zz;
    c3 = (b + 3 < nf4) ? x4[b + 3] : zz;
    c4 = (b + 4 < nf4) ? x4[b + 4] : zz;
  }

  while (active) {
    // issue next tile's loads before computing on the current one
    int tn = t + GRID2;
    bool an = (tn < ntiles);
    float4 n0 = zz, n1 = zz, n2 = zz, n3 = zz, n4 = zz;
    if (an) {
      int b = tn * TILE_F4 + tid * 5;
      n0 = (b + 0 < nf4) ? x4[b + 0] : zz;
      n1 = (b + 1 < nf4) ? x4[b + 1] : zz;
      n2 = (b + 2 < nf4) ? x4[b + 2] : zz;
      n3 = (b + 3 < nf4) ? x4[b + 3] : zz;
      n4 = (b + 4 < nf4) ? x4[b + 4] : zz;
    }

    float v[20] = {c0.x, c0.y, c0.z, c0.w, c1.x, c1.y, c1.z, c1.w,
                   c2.x, c2.y, c2.z, c2.w, c3.x, c3.y, c3.z, c3.w,
                   c4.x, c4.y, c4.z, c4.w};
    int k = 0;
#pragma unroll
    for (int i = 0; i < 10; i++) {
#pragma unroll
      for (int j = 0; j <= i; j++) {
        acc[k] += v[i] * v[j] + v[10 + i] * v[10 + j];
        k++;
      }
    }

    c0 = n0; c1 = n1; c2 = n2; c3 = n3; c4 = n4;
    t = tn;
    active = an;
  }

  __shared__ double sred[4][55];
  int lane = threadIdx.x & 63;
  int wv = threadIdx.x >> 6;
#pragma unroll
  for (int k = 0; k < 55; k++) {
    double d = (double)acc[k];
#pragma unroll
    for (int off = 32; off > 0; off >>= 1) d += __shfl_down(d, off, 64);
    if (lane == 0) sred[wv][k] = d;
  }
  __syncthreads();
  double* gr = g + 55 * (blockIdx.x & 3);  // 4 replicas -> 4x fewer per-address atomics
  if (threadIdx.x < 55) {
    double s = sred[0][threadIdx.x] + sred[1][threadIdx.x] +
               sred[2][threadIdx.x] + sred[3][threadIdx.x];
    atomicAdd(&gr[threadIdx.x], s);
  }
}

// ------------------------- LAPACK helpers (fp32) ---------------------------

__device__ __forceinline__ float sf_sign(float a, float b) {
  return (b >= 0.0f) ? fabsf(a) : -fabsf(a);
}

__device__ __forceinline__ float slapy2(float x, float y) {
  float xa = fabsf(x), ya = fabsf(y);
  float w = fmaxf(xa, ya), z = fminf(xa, ya);
  if (z == 0.0f) return w;
  float q = z / w;
  return w * sqrtf(1.0f + q * q);
}

// LAPACK >= 3.10 slartg: c = |f|/d >= 0, r = sign(f)*d, s = g/r
__device__ __forceinline__ void slartg(float f, float g, float* c, float* s, float* r) {
  if (g == 0.0f) {
    *c = 1.0f; *s = 0.0f; *r = f;
  } else if (f == 0.0f) {
    *c = 0.0f; *s = sf_sign(1.0f, g); *r = fabsf(g);
  } else {
    float d = sqrtf(f * f + g * g);
    *c = fabsf(f) / d;
    float rr = sf_sign(d, f);
    *s = g / rr;
    *r = rr;
  }
}

__device__ __forceinline__ void slaev2(float a, float b, float c,
                                       float* rt1, float* rt2, float* cs1, float* sn1) {
  float sm = a + c;
  float df = a - c;
  float adf = fabsf(df);
  float tb = b + b;
  float ab = fabsf(tb);
  float acmx, acmn;
  if (fabsf(a) > fabsf(c)) { acmx = a; acmn = c; } else { acmx = c; acmn = a; }
  float rt;
  if (adf > ab)      { float t = ab / adf; rt = adf * sqrtf(1.0f + t * t); }
  else if (adf < ab) { float t = adf / ab; rt = ab * sqrtf(1.0f + t * t); }
  else               { rt = ab * sqrtf(2.0f); }
  int sgn1;
  if (sm < 0.0f) {
    *rt1 = 0.5f * (sm - rt); sgn1 = -1;
    *rt2 = (acmx / *rt1) * acmn - (b / *rt1) * b;
  } else if (sm > 0.0f) {
    *rt1 = 0.5f * (sm + rt); sgn1 = 1;
    *rt2 = (acmx / *rt1) * acmn - (b / *rt1) * b;
  } else {
    *rt1 = 0.5f * rt; *rt2 = -0.5f * rt; sgn1 = 1;
  }
  int sgn2;
  float cs;
  if (df >= 0.0f) { cs = df + rt; sgn2 = 1; } else { cs = df - rt; sgn2 = -1; }
  float acs = fabsf(cs);
  if (acs > ab) {
    float ct = -tb / cs;
    *sn1 = 1.0f / sqrtf(1.0f + ct * ct);
    *cs1 = ct * (*sn1);
  } else {
    if (ab == 0.0f) { *cs1 = 1.0f; *sn1 = 0.0f; }
    else {
      float tn = -cs / tb;
      *cs1 = 1.0f / sqrtf(1.0f + tn * tn);
      *sn1 = tn * (*cs1);
    }
  }
  if (sgn1 == sgn2) { float tn = *cs1; *cs1 = -(*sn1); *sn1 = tn; }
}

// 10-way register select / masked write (runtime idx0, 0-based); branch-free.
// Used ONLY outside hot loops (once-per-sweep spots, 2x2 blocks, sort).
__device__ __forceinline__ float sel10(const float* a, int idx0) {
  float v = 0.0f;
#pragma unroll
  for (int k = 0; k < 10; k++) v = (k == idx0) ? a[k] : v;
  return v;
}
__device__ __forceinline__ void put10(float* a, int idx0, float v) {
#pragma unroll
  for (int k = 0; k < 10; k++) a[k] = (k == idx0) ? v : a[k];
}

// static 1-based access macros (indices must be compile-time constants)
#define A_(r, c) Am[((r)-1) * 10 + ((c)-1)]
#define Z_(r, c) Zm[((r)-1) * 10 + ((c)-1)]
#define D_(i) dv[(i)-1]
#define E_(i) ev[(i)-1]
#define TAUV(i) tauv[(i)-1]
#define WV(i) wvv[(i)-1]

__global__ __launch_bounds__(64, 1) void eig_mlp_kernel(
    const double* __restrict__ g,
    const float* __restrict__ W1,
    const float* __restrict__ b1,
    const float* __restrict__ W2,
    const float* __restrict__ b2,
    float* __restrict__ out) {
  if (blockIdx.x != 0) return;
  const int lane = threadIdx.x;
  const int n = 10;
  float Am[100], Zm[100];
  float dv[10], ev[10], tauv[10], wvv[10], csv[10], snv[10];

  // load gram (4 replicas summed in fp64), round to fp32 — uniform on all lanes
  {
    int k = 0;
#pragma unroll
    for (int i = 0; i < 10; i++)
#pragma unroll
      for (int j = 0; j <= i; j++) {
        double v = g[k] + g[55 + k] + g[110 + k] + g[165 + k];
        float f = (float)v;
        Am[i * 10 + j] = f;
        Am[j * 10 + i] = f;
        k++;
      }
  }

  // -------- ssytd2 (UPLO='L'), static, register-resident, uniform --------
#pragma unroll
  for (int i = 1; i <= n - 1; i++) {
    const int nmi = n - i;
    float alpha = A_(i + 1, i);
    float taui = 0.0f;
    if (nmi > 1) {
      float ss = 0.0f;
#pragma unroll
      for (int r = i + 2; r <= n; r++) { float t = A_(r, i); ss += t * t; }
      float xnorm = sqrtf(ss);
      if (xnorm != 0.0f) {
        float beta = -sf_sign(slapy2(alpha, xnorm), alpha);
        taui = (beta - alpha) / beta;
        float sc = 1.0f / (alpha - beta);
#pragma unroll
        for (int r = i + 2; r <= n; r++) A_(r, i) *= sc;
        alpha = beta;
      }
    }
    E_(i) = alpha;
    A_(i + 1, i) = alpha;
    if (taui != 0.0f) {
      A_(i + 1, i) = 1.0f;
#pragma unroll
      for (int r = i + 1; r <= n; r++) {
        float s = 0.0f;
#pragma unroll
        for (int c = i + 1; c <= n; c++) {
          float arc = (r >= c) ? A_(r, c) : A_(c, r);
          s += arc * A_(c, i);
        }
        WV(r) = taui * s;
      }
      float dot = 0.0f;
#pragma unroll
      for (int r = i + 1; r <= n; r++) dot += WV(r) * A_(r, i);
      float al2 = -0.5f * taui * dot;
#pragma unroll
      for (int r = i + 1; r <= n; r++) WV(r) += al2 * A_(r, i);
#pragma unroll
      for (int c = i + 1; c <= n; c++)
#pragma unroll
        for (int r = c; r <= n; r++)
          A_(r, c) -= A_(r, i) * WV(c) + WV(r) * A_(c, i);
      A_(i + 1, i) = E_(i);
    }
    D_(i) = A_(i, i);
    TAUV(i) = taui;
  }
  D_(n) = A_(n, n);

  // -------- form Q0 = H(1)...H(n-1), static, uniform --------
#pragma unroll
  for (int r = 1; r <= n; r++)
#pragma unroll
    for (int c = 1; c <= n; c++) Z_(r, c) = (r == c) ? 1.0f : 0.0f;
#pragma unroll
  for (int i = n - 1; i >= 1; i--) {
    float taui = TAUV(i);
    if (taui != 0.0f) {
#pragma unroll
      for (int c = 1; c <= n; c++) {
        float t = Z_(i + 1, c);
#pragma unroll
        for (int r = i + 2; r <= n; r++) t += A_(r, i) * Z_(r, c);
        t *= taui;
        Z_(i + 1, c) -= t;
#pragma unroll
        for (int r = i + 2; r <= n; r++) Z_(r, c) -= A_(r, i) * t;
      }
    }
  }

  // -------- distribute Z rows: lane r holds row r as z[0..9] --------
  const int r_own = (lane < 10) ? lane : 0;
  float z[10];
#pragma unroll
  for (int k = 0; k < 10; k++) {
    float v = Zm[0 * 10 + k];
#pragma unroll
    for (int rr = 1; rr < 10; rr++) v = (r_own == rr) ? Zm[rr * 10 + k] : v;
    z[k] = v;
  }

  // -------- ssteqr ('V'); sweeps statically unrolled w/ range guards ------
  const float eps = 5.9604644775390625e-08f;      // 2^-24
  const float eps2 = eps * eps;
  const float safmin = 1.17549435082228751e-38f;  // 2^-126
  const int nmaxit = n * 30;
  int jtot = 0;
  int l1 = 1;
  int guard = 0;

  while (l1 <= n && guard++ < 2000) {
    if (l1 > 1) put10(ev, l1 - 2, 0.0f);  // E_(l1-1) = 0
    int m = n;
    {
      bool found = false;
#pragma unroll
      for (int k = 1; k <= n - 1; k++) {
        if (!found && k >= l1) {
          float tst = fabsf(ev[k - 1]);
          if (tst == 0.0f) {
            m = k; found = true;
          } else if (tst <= (sqrtf(fabsf(dv[k - 1])) * sqrtf(fabsf(dv[k]))) * eps) {
            ev[k - 1] = 0.0f;
            m = k; found = true;
          }
        }
      }
    }
    int l = l1, lsv = l, lend = m, lendsv = m;
    l1 = m + 1;
    if (lend == l) continue;
    if (fabsf(sel10(dv, lend - 1)) < fabsf(sel10(dv, l - 1))) { lend = lsv; l = lendsv; }

    if (lend > l) {
      // ---------------- QL iteration ----------------
      for (;;) {
        if (guard++ > 4000) break;
        int m2 = lend;
        if (l != lend) {
          bool fnd = false;
#pragma unroll
          for (int k = 1; k <= n - 1; k++) {
            if (!fnd && k >= l && k <= lend - 1) {
              float e = ev[k - 1];
              if (e * e <= (eps2 * fabsf(dv[k - 1])) * fabsf(dv[k]) + safmin) {
                m2 = k; fnd = true;
              }
            }
          }
        }
        if (m2 < lend) put10(ev, m2 - 1, 0.0f);
        float p = sel10(dv, l - 1);
        if (m2 == l) {  // eigenvalue found
          put10(dv, l - 1, p);
          l = l + 1;
          if (l <= lend) continue;
          break;
        }
        if (m2 == l + 1) {  // 2x2 block; 0-based cols (l, l-1)
          float rt1, rt2, c2, s2;
          slaev2(sel10(dv, l - 1), sel10(ev, l - 1), sel10(dv, l), &rt1, &rt2, &c2, &s2);
          float a = sel10(z, l);
          float b = sel10(z, l - 1);
          put10(z, l, c2 * a - s2 * b);
          put10(z, l - 1, s2 * a + c2 * b);
          put10(dv, l - 1, rt1);
          put10(dv, l, rt2);
          put10(ev, l - 1, 0.0f);
          l = l + 2;
          if (l <= lend) continue;
          break;
        }
        if (jtot == nmaxit) break;
        jtot++;
        float El = sel10(ev, l - 1);
        float gg = (sel10(dv, l) - p) / (2.0f * El);
        float rr = slapy2(gg, 1.0f);
        gg = sel10(dv, m2 - 1) - p + (El / (gg + sf_sign(rr, gg)));
        float s = 1.0f, c = 1.0f;
        p = 0.0f;
        // rotation recurrence, static descending unroll w/ scalar guards
#pragma unroll
        for (int i = n - 1; i >= 1; i--) {
          if (i <= m2 - 1 && i >= l) {
            float e = ev[i - 1];
            float f = s * e, b = c * e;
            slartg(gg, f, &c, &s, &rr);
            if (i != m2 - 1) ev[i] = rr;  // E_(i+1), static
            gg = dv[i] - p;               // D_(i+1)
            rr = (dv[i - 1] - gg) * s + 2.0f * c * b;
            p = s * rr;
            dv[i] = gg + p;
            gg = c * rr - b;
            csv[i - 1] = c;
            snv[i - 1] = -s;
          }
        }
        // apply rotations (slasr 'B'): descending j, 0-based cols (j, j-1)
        {
          float a = sel10(z, m2 - 1);  // carried updated value of col j
#pragma unroll
          for (int j = n - 1; j >= 1; j--) {
            if (j <= m2 - 1 && j >= l) {
              float cj = csv[j - 1], sj = snv[j - 1];  // static
              float b = z[j - 1];                      // untouched original
              z[j] = cj * a - sj * b;                  // final col j
              a = sj * a + cj * b;                     // new col j-1, carried
            }
          }
          put10(z, l - 1, a);
        }
        put10(dv, l - 1, sel10(dv, l - 1) - p);
        put10(ev, l - 1, gg);
      }
    } else {
      // ---------------- QR iteration ----------------
      for (;;) {
        if (guard++ > 4000) break;
        int m2 = lend;
        if (l != lend) {
          bool fnd = false;
#pragma unroll
          for (int k = n; k >= 2; k--) {
            if (!fnd && k <= l && k >= lend + 1) {
              float e = ev[k - 2];
              if (e * e <= (eps2 * fabsf(dv[k - 1])) * fabsf(dv[k - 2]) + safmin) {
                m2 = k; fnd = true;
              }
            }
          }
        }
        if (m2 > lend) put10(ev, m2 - 2, 0.0f);  // E_(m2-1) = 0
        float p = sel10(dv, l - 1);
        if (m2 == l) {  // eigenvalue found
          put10(dv, l - 1, p);
          l = l - 1;
          if (l >= lend) continue;
          break;
        }
        if (m2 == l - 1) {  // 2x2 block; 0-based cols (l-1, l-2)
          float rt1, rt2, c2, s2;
          slaev2(sel10(dv, l - 2), sel10(ev, l - 2), sel10(dv, l - 1), &rt1, &rt2, &c2, &s2);
          float a = sel10(z, l - 1);
          float b = sel10(z, l - 2);
          put10(z, l - 1, c2 * a - s2 * b);
          put10(z, l - 2, s2 * a + c2 * b);
          put10(dv, l - 2, rt1);
          put10(dv, l - 1, rt2);
          put10(ev, l - 2, 0.0f);
          l = l - 2;
          if (l >= lend) continue;
          break;
        }
        if (jtot == nmaxit) break;
        jtot++;
        float El1 = sel10(ev, l - 2);  // E_(l-1)
        float gg = (sel10(dv, l - 2) - p) / (2.0f * El1);
        float rr = slapy2(gg, 1.0f);
        gg = sel10(dv, m2 - 1) - p + (El1 / (gg + sf_sign(rr, gg)));
        float s = 1.0f, c = 1.0f;
        p = 0.0f;
        // rotation recurrence, static ascending unroll w/ scalar guards
#pragma unroll
        for (int i = 1; i <= n - 1; i++) {
          if (i >= m2 && i <= l - 1) {
            float e = ev[i - 1];
            float f = s * e, b = c * e;
            slartg(gg, f, &c, &s, &rr);
            if (i >= 2) {
              if (i != m2) ev[i - 2] = rr;  // E_(i-1), static
            }
            gg = dv[i - 1] - p;  // D_(i)
            rr = (dv[i] - gg) * s + 2.0f * c * b;
            p = s * rr;
            dv[i - 1] = gg + p;
            gg = c * rr - b;
            csv[i - 1] = c;
            snv[i - 1] = s;
          }
        }
        // apply rotations (slasr 'F'): ascending j, 0-based cols (j, j-1)
        {
          float carry = sel10(z, m2 - 1);  // current value of col j-1
#pragma unroll
          for (int j = 1; j <= n - 1; j++) {
            if (j >= m2 && j <= l - 1) {
              float cj = csv[j - 1], sj = snv[j - 1];  // static
              float t = z[j];                          // untouched original
              z[j - 1] = sj * t + cj * carry;          // final col j-1
              carry = cj * t - sj * carry;             // new col j, carried
            }
          }
          put10(z, l - 1, carry);
        }
        put10(dv, l - 1, sel10(dv, l - 1) - p);
        put10(ev, l - 2, gg);  // E_(l-1)
      }
    }
  }

  // -------- selection sort ascending (as in ssteqr), uniform --------
  for (int ii = 2; ii <= n; ii++) {
    int i = ii - 1;
    int k = i;
    float p = sel10(dv, i - 1);
    for (int j = ii; j <= n; j++) {
      float dj = sel10(dv, j - 1);
      if (dj < p) { k = j; p = dj; }
    }
    if (k != i) {
      float di = sel10(dv, i - 1);
      put10(dv, k - 1, di);
      put10(dv, i - 1, p);
      float a = sel10(z, i - 1), b = sel10(z, k - 1);
      put10(z, i - 1, b);
      put10(z, k - 1, a);
    }
  }

  // -------- MLP per lane (lane r computes output row r) --------
  if (lane < 10) {
    double o = (double)b2[0];
#pragma unroll
    for (int h = 0; h < 16; h++) {
      double sgm = (double)b1[h];
#pragma unroll
      for (int k = 0; k < 10; k++) sgm += (double)z[k] * (double)W1[h * 10 + k];
      if (sgm > 0.0) o += sgm * (double)W2[h];
    }
    double sig = 1.0 / (1.0 + exp(-o));
    out[lane] = (float)(0.5 * (sig + 1.0));
  }
}

extern "C" void kernel_launch(void* const* d_in, const int* in_sizes, int n_in,
                              void* d_out, int out_size, void* d_ws, size_t ws_size,
                              hipStream_t stream) {
  const float* x  = (const float*)d_in[0];
  const float* W1 = (const float*)d_in[1];
  const float* b1 = (const float*)d_in[2];
  const float* W2 = (const float*)d_in[3];
  const float* b2 = (const float*)d_in[4];
  double* g = (double*)d_ws;
  float* out = (float*)d_out;

  int nf4 = in_sizes[0] / 4;  // 10M float4

  zero_ws_kernel<<<1, 256, 0, stream>>>(g);
  gram_kernel<<<GRID2, BLK2, 0, stream>>>((const float4*)x, g, nf4);
  eig_mlp_kernel<<<1, 64, 0, stream>>>(g, W1, b1, W2, b2, out);
}